// Round 1
// baseline (598.722 us; speedup 1.0000x reference)
//
#include <hip/hip_runtime.h>
#include <hip/hip_bf16.h>

// Problem constants
#define B_   16
#define C_   256
#define H_   128
#define W_   128
#define H2_  65
#define W2_  65
#define K_   1024          // 4*C
#define MTOT 67600         // B_*H2_*W2_

typedef __attribute__((ext_vector_type(8))) short bf16x8;
typedef __attribute__((ext_vector_type(4))) float f32x4;

// reversed db2 decomposition filters: out[i] = sum_k fr[k] * x[sym(2i-2+k)]
__device__ __constant__ float FRLO[4] = {0.48296291314469025f, 0.836516303737469f,
                                         0.22414386804185735f, -0.12940952255092145f};
__device__ __constant__ float FRHI[4] = {-0.12940952255092145f, -0.22414386804185735f,
                                         0.836516303737469f, -0.48296291314469025f};

// ---------------------------------------------------------------------------
// Kernel 1: DWT. Block: 256 threads, handles (b, h, 16-channel tile).
// Stages 16ch x 4rows x 128cols f32 in LDS, computes LL/LH/HL/HH for 65 w2
// positions, writes bf16 A[m][k] with m=(b*65+h)*65+w2, k = s*256 + c.
// ---------------------------------------------------------------------------
__global__ __launch_bounds__(256) void dwt_kernel(const float* __restrict__ x,
                                                  __hip_bfloat16* __restrict__ A) {
    const int c0 = blockIdx.x * 16;
    const int h  = blockIdx.y;
    const int b  = blockIdx.z;
    const int t  = threadIdx.x;

    __shared__ float xs[16 * 4 * 129];   // row stride 129 floats (pad +1)

    // symmetric row indices for this h
    int srow[4];
#pragma unroll
    for (int r = 0; r < 4; ++r) {
        int m = 2 * h - 2 + r;
        if (m < 0) m = -1 - m;
        if (m > 127) m = 255 - m;
        srow[r] = m;
    }

    // load 16*4*128 = 8192 floats, coalesced
    const float* xb = x + ((size_t)(b * C_ + c0)) * (H_ * W_);
#pragma unroll
    for (int i = 0; i < 32; ++i) {
        int idx = i * 256 + t;
        int col = idx & 127;
        int r   = (idx >> 7) & 3;
        int c   = idx >> 9;          // 0..15
        xs[(c * 4 + r) * 129 + col] = xb[(size_t)c * (H_ * W_) + srow[r] * W_ + col];
    }
    __syncthreads();

    const int c_loc = t & 15;
    const int w2l   = t >> 4;        // 0..15

#pragma unroll
    for (int p = 0; p < 5; ++p) {
        int w2 = p * 16 + w2l;
        if (w2 < W2_) {
            // symmetric col indices
            int cs[4];
#pragma unroll
            for (int j = 0; j < 4; ++j) {
                int cm = 2 * w2 - 2 + j;
                if (cm < 0) cm = -1 - cm;
                if (cm > 127) cm = 255 - cm;
                cs[j] = cm;
            }
            float lo[4], hi[4];
#pragma unroll
            for (int r = 0; r < 4; ++r) {
                float al = 0.f, ah = 0.f;
#pragma unroll
                for (int j = 0; j < 4; ++j) {
                    float v = xs[(c_loc * 4 + r) * 129 + cs[j]];
                    al += FRLO[j] * v;
                    ah += FRHI[j] * v;
                }
                lo[r] = al; hi[r] = ah;
            }
            float LL = 0.f, LH = 0.f, HL = 0.f, HH = 0.f;
#pragma unroll
            for (int r = 0; r < 4; ++r) {
                LL += FRLO[r] * lo[r];
                LH += FRHI[r] * lo[r];
                HL += FRLO[r] * hi[r];
                HH += FRHI[r] * hi[r];
            }
            size_t m = ((size_t)(b * H2_ + h)) * W2_ + w2;
            __hip_bfloat16* Ar = A + m * K_ + (c0 + c_loc);
            Ar[0]       = __float2bfloat16(LL);
            Ar[C_]      = __float2bfloat16(LH);
            Ar[2 * C_]  = __float2bfloat16(HL);
            Ar[3 * C_]  = __float2bfloat16(HH);
        }
    }
}

// ---------------------------------------------------------------------------
// Kernel 2: weight f32 -> bf16 (layout preserved: [n=256][k=1024])
// ---------------------------------------------------------------------------
__global__ __launch_bounds__(256) void wconv_kernel(const float* __restrict__ w,
                                                    __hip_bfloat16* __restrict__ wb) {
    int i = blockIdx.x * 256 + threadIdx.x;   // grid sized exactly: 1024*256 = 262144
    wb[i] = __float2bfloat16(w[i]);
}

// ---------------------------------------------------------------------------
// Kernel 3: GEMM out[m][n] = sum_k A[m][k] * WB[n][k]
// M=67600, N=256, K=1024. Block 256 thr = 4 waves (2x2), wave tile 64x64,
// 4x4 fragments of mfma_f32_16x16x32_bf16. No LDS: frags loaded direct
// (16 full 64B lines per load instr), operands L1/L2 resident.
// k-index convention kappa = 8*(lane>>4)+j applied identically to A and B
// => correct for ANY hardware k-permutation.
// ---------------------------------------------------------------------------
__global__ __launch_bounds__(256) void gemm_kernel(const __hip_bfloat16* __restrict__ A,
                                                   const __hip_bfloat16* __restrict__ WB,
                                                   float* __restrict__ out) {
    const int lane = threadIdx.x & 63;
    const int wid  = threadIdx.x >> 6;
    const int lrow = lane & 15;
    const int lgrp = lane >> 4;
    const int wave_m = wid >> 1;
    const int wave_n = wid & 1;
    const int m_base = blockIdx.x * 128 + wave_m * 64;
    const int n_base = blockIdx.y * 128 + wave_n * 64;

    f32x4 acc[4][4];
#pragma unroll
    for (int mi = 0; mi < 4; ++mi)
#pragma unroll
        for (int ni = 0; ni < 4; ++ni)
            acc[mi][ni] = (f32x4){0.f, 0.f, 0.f, 0.f};

    const short* Ap[4];
    const short* Bp[4];
#pragma unroll
    for (int mi = 0; mi < 4; ++mi) {
        int m = m_base + mi * 16 + lrow;
        if (m > MTOT - 1) m = MTOT - 1;              // clamp: tail rows duplicated, stores guarded
        Ap[mi] = (const short*)A + (size_t)m * K_ + lgrp * 8;
    }
#pragma unroll
    for (int ni = 0; ni < 4; ++ni) {
        int n = n_base + ni * 16 + lrow;             // always < 256
        Bp[ni] = (const short*)WB + (size_t)n * K_ + lgrp * 8;
    }

    for (int kt = 0; kt < K_ / 32; ++kt) {
        bf16x8 a[4], bb[4];
#pragma unroll
        for (int mi = 0; mi < 4; ++mi)
            a[mi] = *(const bf16x8*)(Ap[mi] + kt * 32);
#pragma unroll
        for (int ni = 0; ni < 4; ++ni)
            bb[ni] = *(const bf16x8*)(Bp[ni] + kt * 32);
#pragma unroll
        for (int mi = 0; mi < 4; ++mi)
#pragma unroll
            for (int ni = 0; ni < 4; ++ni)
                acc[mi][ni] = __builtin_amdgcn_mfma_f32_16x16x32_bf16(
                    a[mi], bb[ni], acc[mi][ni], 0, 0, 0);
    }

    // epilogue: D row = 4*lgrp + r, col = lrow (m89-verified C/D layout)
#pragma unroll
    for (int mi = 0; mi < 4; ++mi) {
#pragma unroll
        for (int ni = 0; ni < 4; ++ni) {
            int n  = n_base + ni * 16 + lrow;
            int m0 = m_base + mi * 16 + lgrp * 4;
#pragma unroll
            for (int r = 0; r < 4; ++r) {
                int m = m0 + r;
                if (m < MTOT) {
                    int bidx = m / 4225;             // 4225 = 65*65
                    int rm   = m - bidx * 4225;
                    out[((size_t)(bidx * C_ + n)) * 4225 + rm] = acc[mi][ni][r];
                }
            }
        }
    }
}

// ---------------------------------------------------------------------------
extern "C" void kernel_launch(void* const* d_in, const int* in_sizes, int n_in,
                              void* d_out, int out_size, void* d_ws, size_t ws_size,
                              hipStream_t stream) {
    const float* x = (const float*)d_in[0];
    const float* w = (const float*)d_in[1];
    float* out = (float*)d_out;

    __hip_bfloat16* A  = (__hip_bfloat16*)d_ws;                       // 67600*1024*2 B
    __hip_bfloat16* WB = (__hip_bfloat16*)((char*)d_ws + (size_t)MTOT * K_ * 2);

    dwt_kernel<<<dim3(C_ / 16, H2_, B_), 256, 0, stream>>>(x, A);
    wconv_kernel<<<dim3((C_ * K_) / 256), 256, 0, stream>>>(w, WB);
    gemm_kernel<<<dim3((MTOT + 127) / 128, 2), 256, 0, stream>>>(A, WB, out);
}

// Round 2
// 474.915 us; speedup vs baseline: 1.2607x; 1.2607x over previous
//
#include <hip/hip_runtime.h>
#include <hip/hip_bf16.h>

// Problem constants
#define B_   16
#define C_   256
#define H_   128
#define W_   128
#define H2_  65
#define W2_  65
#define K_   1024          // 4*C
#define MTOT 67600         // B_*H2_*W2_

typedef __attribute__((ext_vector_type(8))) short bf16x8;
typedef __attribute__((ext_vector_type(4))) float f32x4;

// reversed db2 decomposition filters: out[i] = sum_k fr[k] * x[sym(2i-2+k)]
__device__ __constant__ float FRLO[4] = {0.48296291314469025f, 0.836516303737469f,
                                         0.22414386804185735f, -0.12940952255092145f};
__device__ __constant__ float FRHI[4] = {-0.12940952255092145f, -0.22414386804185735f,
                                         0.836516303737469f, -0.48296291314469025f};

__device__ __forceinline__ unsigned short f2bf(float f) {
    __hip_bfloat16 h = __float2bfloat16(f);
    return *reinterpret_cast<unsigned short*>(&h);
}

#define GLL16(g, l)                                                         \
    __builtin_amdgcn_global_load_lds(                                       \
        (const __attribute__((address_space(1))) void*)(g),                 \
        (__attribute__((address_space(3))) void*)(l), 16, 0, 0)

// ---------------------------------------------------------------------------
// Kernel 1: DWT. Block: 256 threads, handles (b, h-pair, 16-channel tile).
// Stages 16ch x 6 input rows x 128 cols f32 in LDS (float4 loads), computes
// output rows h0=2*hp and h1=2*hp+1 for all 65 w2.
// A layout: A[m][k'] with k' = c*4 + s  (s: 0=LL,1=LH,2=HL,3=HH)
// -> one contiguous ushort4 store per (thread, w2, h).
// LDS layout: c stride 804 floats (16B-aligned, 4 mod 32 -> <=4-way), row
// stride 132 floats.
// ---------------------------------------------------------------------------
__global__ __launch_bounds__(256) void dwt_kernel(const float* __restrict__ x,
                                                  __hip_bfloat16* __restrict__ A) {
    const int c0 = blockIdx.x * 16;
    const int hp = blockIdx.y;          // 0..32
    const int b  = blockIdx.z;
    const int t  = threadIdx.x;

    __shared__ float xs[16 * 804];

    // symmetric input row indices: local r=0..5 -> global 4*hp-2+r, reflected
    int srow[6];
#pragma unroll
    for (int r = 0; r < 6; ++r) {
        int m = 4 * hp - 2 + r;
        if (m < 0) m = -1 - m;
        if (m > 127) m = 255 - m;
        srow[r] = m;
    }

    // stage: 16ch * 6rows * 32 float4 = 3072 float4 = 12 iters * 256 threads
    const float* xb = x + ((size_t)(b * C_ + c0)) * (H_ * W_);
#pragma unroll
    for (int it = 0; it < 12; ++it) {
        int idx = it * 256 + t;
        int q   = idx & 31;          // float4 col
        int rc  = idx >> 5;          // 0..95
        int c   = rc / 6;
        int r   = rc - c * 6;
        float4 v = *(const float4*)(xb + (size_t)c * (H_ * W_) + srow[r] * W_ + q * 4);
        *(float4*)(&xs[c * 804 + r * 132 + q * 4]) = v;
    }
    __syncthreads();

    const int c_loc = t & 15;
    const int w2l   = t >> 4;           // 0..15
    const float* xc = xs + c_loc * 804;
    const int h0 = 2 * hp, h1 = 2 * hp + 1;
    unsigned short* Ag = (unsigned short*)A + (size_t)(c0 + c_loc) * 4;

#pragma unroll
    for (int p = 0; p < 5; ++p) {
        int w2 = p * 16 + w2l;
        if (w2 >= W2_) continue;
        int cs[4];
#pragma unroll
        for (int j = 0; j < 4; ++j) {
            int cm = 2 * w2 - 2 + j;
            if (cm < 0) cm = -1 - cm;
            if (cm > 127) cm = 255 - cm;
            cs[j] = cm;
        }
        float lo[6], hi[6];
#pragma unroll
        for (int r = 0; r < 6; ++r) {
            float a0 = 0.f, a1 = 0.f;
#pragma unroll
            for (int j = 0; j < 4; ++j) {
                float v = xc[r * 132 + cs[j]];
                a0 += FRLO[j] * v;
                a1 += FRHI[j] * v;
            }
            lo[r] = a0; hi[r] = a1;
        }
        // output row h0 uses local rows 0..3
        {
            float LL = 0.f, LH = 0.f, HL = 0.f, HH = 0.f;
#pragma unroll
            for (int r = 0; r < 4; ++r) {
                LL += FRLO[r] * lo[r];
                LH += FRHI[r] * lo[r];
                HL += FRLO[r] * hi[r];
                HH += FRHI[r] * hi[r];
            }
            size_t m = ((size_t)(b * H2_ + h0)) * W2_ + w2;
            ushort4 v4 = {f2bf(LL), f2bf(LH), f2bf(HL), f2bf(HH)};
            *(ushort4*)(Ag + m * K_) = v4;
        }
        // output row h1 uses local rows 2..5
        if (h1 < H2_) {
            float LL = 0.f, LH = 0.f, HL = 0.f, HH = 0.f;
#pragma unroll
            for (int r = 0; r < 4; ++r) {
                LL += FRLO[r] * lo[r + 2];
                LH += FRHI[r] * lo[r + 2];
                HL += FRLO[r] * hi[r + 2];
                HH += FRHI[r] * hi[r + 2];
            }
            size_t m = ((size_t)(b * H2_ + h1)) * W2_ + w2;
            ushort4 v4 = {f2bf(LL), f2bf(LH), f2bf(HL), f2bf(HH)};
            *(ushort4*)(Ag + m * K_) = v4;
        }
    }
}

// ---------------------------------------------------------------------------
// Kernel 2: weight f32 -> bf16 with k-permutation:
// WB[n][k'=c*4+s] = w[n][s*256+c]
// ---------------------------------------------------------------------------
__global__ __launch_bounds__(256) void wconv_kernel(const float* __restrict__ w,
                                                    __hip_bfloat16* __restrict__ wb) {
    int i  = blockIdx.x * 256 + threadIdx.x;   // 0..262143
    int n  = i >> 10;
    int kp = i & 1023;
    int c  = kp >> 2;
    int s  = kp & 3;
    wb[i] = __float2bfloat16(w[n * 1024 + s * 256 + c]);
}

// ---------------------------------------------------------------------------
// Kernel 3: GEMM out[m][n] = sum_k A[m][k]*WB[n][k].  M=67600, N=256, K=1024.
// m97-pattern: block 512 thr = 8 waves (2x4), tile 128x256 (full N -> A read
// exactly once), BK=32 single-buffered LDS via global_load_lds width=16.
// kappa = lgrp*8+j applied identically to A and B fragments.
// ---------------------------------------------------------------------------
__global__ __launch_bounds__(512) void gemm_kernel(const __hip_bfloat16* __restrict__ A,
                                                   const __hip_bfloat16* __restrict__ WB,
                                                   float* __restrict__ out) {
    __shared__ __hip_bfloat16 As[128 * 32];
    __shared__ __hip_bfloat16 Bs[256 * 32];

    const int tid  = threadIdx.x;
    const int lane = tid & 63;
    const int wid  = tid >> 6;
    const int lrow = lane & 15;
    const int lgrp = lane >> 4;
    const int wave_m = wid >> 2;        // 0..1
    const int wave_n = wid & 3;         // 0..3
    const int m0 = blockIdx.x * 128;

    // staging source/dest (constant over kt except +kt*32 on src)
    int arow = m0 + (tid >> 2);
    if (arow > MTOT - 1) arow = MTOT - 1;          // tail clamp (stores guarded)
    const short* gA  = (const short*)A  + (size_t)arow * K_ + (tid & 3) * 8;
    const short* gB0 = (const short*)WB + (size_t)(tid >> 2) * K_ + (tid & 3) * 8;
    const short* gB1 = (const short*)WB + (size_t)(128 + (tid >> 2)) * K_ + (tid & 3) * 8;
    __hip_bfloat16* dA  = As + tid * 8;            // = wave-uniform base + lane*16B
    __hip_bfloat16* dB0 = Bs + tid * 8;
    __hip_bfloat16* dB1 = Bs + (512 + tid) * 8;

    f32x4 acc[4][4];
#pragma unroll
    for (int mi = 0; mi < 4; ++mi)
#pragma unroll
        for (int ni = 0; ni < 4; ++ni)
            acc[mi][ni] = (f32x4){0.f, 0.f, 0.f, 0.f};

    const __hip_bfloat16* aBase = As + (wave_m * 64 + lrow) * 32 + lgrp * 8;
    const __hip_bfloat16* bBase = Bs + (wave_n * 64 + lrow) * 32 + lgrp * 8;

    for (int kt = 0; kt < K_ / 32; ++kt) {
        GLL16(gA  + kt * 32, dA);
        GLL16(gB0 + kt * 32, dB0);
        GLL16(gB1 + kt * 32, dB1);
        __syncthreads();               // compiler drains vmcnt before barrier

        bf16x8 a[4], bb[4];
#pragma unroll
        for (int mi = 0; mi < 4; ++mi)
            a[mi] = *(const bf16x8*)(aBase + mi * 16 * 32);
#pragma unroll
        for (int ni = 0; ni < 4; ++ni)
            bb[ni] = *(const bf16x8*)(bBase + ni * 16 * 32);
#pragma unroll
        for (int mi = 0; mi < 4; ++mi)
#pragma unroll
            for (int ni = 0; ni < 4; ++ni)
                acc[mi][ni] = __builtin_amdgcn_mfma_f32_16x16x32_bf16(
                    a[mi], bb[ni], acc[mi][ni], 0, 0, 0);
        __syncthreads();
    }

    // epilogue: D row = 4*lgrp + r, col = lrow (m89-verified C/D layout)
#pragma unroll
    for (int mi = 0; mi < 4; ++mi) {
#pragma unroll
        for (int ni = 0; ni < 4; ++ni) {
            int n  = wave_n * 64 + ni * 16 + lrow;
            int mb = m0 + wave_m * 64 + mi * 16 + lgrp * 4;
#pragma unroll
            for (int r = 0; r < 4; ++r) {
                int m = mb + r;
                if (m < MTOT) {
                    int bidx = m / 4225;             // 4225 = 65*65
                    int rm   = m - bidx * 4225;
                    out[((size_t)(bidx * C_ + n)) * 4225 + rm] = acc[mi][ni][r];
                }
            }
        }
    }
}

// ---------------------------------------------------------------------------
extern "C" void kernel_launch(void* const* d_in, const int* in_sizes, int n_in,
                              void* d_out, int out_size, void* d_ws, size_t ws_size,
                              hipStream_t stream) {
    const float* x = (const float*)d_in[0];
    const float* w = (const float*)d_in[1];
    float* out = (float*)d_out;

    __hip_bfloat16* A  = (__hip_bfloat16*)d_ws;                       // 67600*1024*2 B
    __hip_bfloat16* WB = (__hip_bfloat16*)((char*)d_ws + (size_t)MTOT * K_ * 2);

    dwt_kernel<<<dim3(C_ / 16, 33, B_), 256, 0, stream>>>(x, A);
    wconv_kernel<<<dim3((C_ * K_) / 256), 256, 0, stream>>>(w, WB);
    gemm_kernel<<<dim3((MTOT + 127) / 128), 512, 0, stream>>>(A, WB, out);
}